// Round 8
// baseline (148.389 us; speedup 1.0000x reference)
//
#include <hip/hip_runtime.h>

// CharRNN GRU: B=4096, T=256, V=256, H=20, L=15, reset_after=True, drop_rate=0.
// f32 in / f32 out. 3 batches per wave (20 lanes each); NO LDS memory traffic
// in the recurrence: h exchanged via ds_bpermute (crossbar only), U packed
// bf16 in 30 VGPRs, recurrent dot via v_dot2_f32_bf16 (f32 accum).
// log2(e) folded into tables: activations are rcp(1 + v_exp_f32(s)).
// x / xW LDS gathers are prefetched one step ahead (off the critical path).

#define BB 4096
#define TT 256
#define VV 256
#define HH 20
#define G3 60    // 3*H
#define LL 15
#define NBATCH 12             // batches per block (4 waves x 3)
#define NTHREADS 256
#define LOG2E 1.44269504088896340736f

__device__ __forceinline__ unsigned short f2bf(float f) {
    union { float f; unsigned int i; } c;
    c.f = f;
    unsigned int x = c.i;
    return (unsigned short)((x + 0x7FFFu + ((x >> 16) & 1u)) >> 16); // RNE
}

__device__ __forceinline__ unsigned pack2bf(float a, float b) {
    return (unsigned)f2bf(a) | ((unsigned)f2bf(b) << 16);
}

__device__ __forceinline__ float fast_rcp(float x) {
#if __has_builtin(__builtin_amdgcn_rcpf)
    return __builtin_amdgcn_rcpf(x);
#else
    return 1.0f / x;
#endif
}

// crossbar pull: result = src-register of lane (byteaddr>>2); no LDS memory
__device__ __forceinline__ float bperm(int byteaddr, float v) {
    return __int_as_float(__builtin_amdgcn_ds_bpermute(byteaddr, __float_as_int(v)));
}

// D = a.x*b.x + a.y*b.y + c  (bf16 pairs packed in u32, f32 accumulate)
__device__ __forceinline__ float dot2bf(unsigned a, unsigned b, float c) {
    float d;
    asm("v_dot2_f32_bf16 %0, %1, %2, %3" : "=v"(d) : "v"(a), "v"(b), "v"(c));
    return d;
}

// pack two f32 into bf16 pair: lo = a, hi = b
__device__ __forceinline__ unsigned cvtpk(float a, float b) {
    unsigned r;
    asm("v_cvt_pk_bf16_f32 %0, %1, %2" : "=v"(r) : "v"(a), "v"(b));
    return r;
}

// 2^x, single instruction
__device__ __forceinline__ float exp2i(float x) {
    float r;
    asm("v_exp_f32 %0, %1" : "=v"(r) : "v"(x));
    return r;
}

__global__ __launch_bounds__(NTHREADS, 2) void gru_kernel(
    const int* __restrict__ x,            // [B][T] int32
    const float* __restrict__ kernelW,    // [V][3H] f32
    const float* __restrict__ rkernel,    // [H][3H] f32
    const float* __restrict__ bias,       // [2][3H] f32
    const float* __restrict__ dense_w,    // [H][L] f32
    const float* __restrict__ dense_b,    // [L] f32
    float* __restrict__ out)              // [B][L] f32
{
    // z/r parts pre-scaled by -log2(e)  (sigmoid(s) = rcp(1+2^(-log2e*s)))
    // h  part pre-scaled by +2*log2(e)  (tanh(y)   = 1-2*rcp(1+2^(2*log2e*y)))
    __shared__ int2  xwall[VV * HH];      // {bf16(z)|bf16(r)<<16, f32 h}: 40960 B
    __shared__ float u_lds[HH * G3];      // staging only (packed into VGPRs)
    __shared__ float w_lds[HH * LL];
    __shared__ float db_lds[LL];
    __shared__ int   x_lds[NBATCH][TT + 1];   // +1: valid prefetch at t=TT-1

    const int tid = threadIdx.x;
    const long b0 = (long)blockIdx.x * NBATCH;

    // ---- staging (one barrier total) ----
    for (int idx = tid; idx < VV * HH; idx += NTHREADS) {
        const int v = idx / HH, j = idx - v * HH;
        const float vz = (kernelW[v * G3 + j]          + bias[j])          * (-LOG2E);
        const float vr = (kernelW[v * G3 + HH + j]     + bias[HH + j])     * (-LOG2E);
        const float vh = (kernelW[v * G3 + 2 * HH + j] + bias[2 * HH + j]) * (2.0f * LOG2E);
        int2 pk;
        pk.x = (int)pack2bf(vz, vr);
        pk.y = __float_as_int(vh);
        xwall[idx] = pk;
    }
    for (int idx = tid; idx < HH * G3; idx += NTHREADS) u_lds[idx] = rkernel[idx];
    for (int idx = tid; idx < HH * LL; idx += NTHREADS) w_lds[idx] = dense_w[idx];
    if (tid < LL) db_lds[tid] = dense_b[tid];
    for (int k = tid; k < NBATCH * (TT + 1); k += NTHREADS) {
        const int b = k / (TT + 1), tt = k - b * (TT + 1);
        x_lds[b][tt] = (tt < TT && (b0 + b) < BB) ? x[(b0 + b) * TT + tt] : 0;
    }
    __syncthreads();   // the ONLY block barrier

    const int lane = tid & 63;
    const int g3   = lane / 20;            // 0..2 active, 3 for idle lanes 60-63
    const int j    = lane - g3 * 20;
    const bool active = (lane < 60);
    const int lb   = (tid >> 6) * 3 + g3;  // local batch
    const int lbc  = active ? lb : 0;
    const int ba   = 80 * g3;              // byte addr of group lane 0 (lane*4)

    // recurrent kernel columns j, H+j, 2H+j packed bf16 over i-pairs (30 VGPRs)
    // z/r scaled by -log2e, h scaled by +2log2e (folded activations)
    unsigned Uz[10], Ur[10], Uh[10];
    #pragma unroll
    for (int q = 0; q < 10; ++q) {
        Uz[q] = pack2bf(u_lds[(2*q) * G3 + j]        * (-LOG2E),
                        u_lds[(2*q+1) * G3 + j]      * (-LOG2E));
        Ur[q] = pack2bf(u_lds[(2*q) * G3 + HH + j]   * (-LOG2E),
                        u_lds[(2*q+1) * G3 + HH + j] * (-LOG2E));
        Uh[q] = pack2bf(u_lds[(2*q) * G3 + 2*HH + j]   * (2.0f * LOG2E),
                        u_lds[(2*q+1) * G3 + 2*HH + j] * (2.0f * LOG2E));
    }
    const float brz = bias[G3 + j]          * (-LOG2E);
    const float brr = bias[G3 + HH + j]     * (-LOG2E);
    const float brh = bias[G3 + 2 * HH + j] * (2.0f * LOG2E);

    float hmine = 0.0f;
    const int* xrow = x_lds[lbc];

    // prefetch step 0's gather
    int  xvn = xrow[0];
    int2 wn  = xwall[xvn * HH + j];

    for (int t = 0; t < TT; ++t) {
        const int2 w = wn;

        // ---- h exchange: crossbar only (20 bpermute), then pack pairs ----
        unsigned hp[10];
        #pragma unroll
        for (int q = 0; q < 10; ++q) {
            const float he = bperm(ba + 8 * q,     hmine);
            const float ho = bperm(ba + 8 * q + 4, hmine);
            hp[q] = cvtpk(he, ho);
        }

        // ---- prefetch next step's gather (hidden under compute) ----
        const int xv2 = xrow[t + 1];           // index TT is valid (pad)
        wn = xwall[xv2 * HH + j];

        const float xz = __uint_as_float(((unsigned)w.x) << 16);
        const float xr = __uint_as_float(((unsigned)w.x) & 0xffff0000u);
        const float xh = __int_as_float(w.y);

        // ---- two dot2 chains per gate ----
        float za = brz, ra = brr, ha = brh;
        float zb = 0.f, rb = 0.f, hb = 0.f;
        #pragma unroll
        for (int q = 0; q < 5; ++q) {
            za = dot2bf(hp[q], Uz[q], za);
            ra = dot2bf(hp[q], Ur[q], ra);
            ha = dot2bf(hp[q], Uh[q], ha);
        }
        #pragma unroll
        for (int q = 5; q < 10; ++q) {
            zb = dot2bf(hp[q], Uz[q], zb);
            rb = dot2bf(hp[q], Ur[q], rb);
            hb = dot2bf(hp[q], Uh[q], hb);
        }

        // ---- folded activations: one v_exp + one v_rcp each ----
        const float z  = fast_rcp(1.0f + exp2i(xz + (za + zb)));   // sigmoid
        const float r  = fast_rcp(1.0f + exp2i(xr + (ra + rb)));   // sigmoid
        const float yh = fmaf(r, ha + hb, xh);                     // 2log2e-scaled
        const float hc = fmaf(-2.0f, fast_rcp(1.0f + exp2i(yh)), 1.0f); // tanh
        hmine = hc + z * (hmine - hc);
    }

    // ---- collect final h via crossbar for the dense head ----
    float hf[HH];
    #pragma unroll
    for (int i = 0; i < HH; ++i) hf[i] = bperm(ba + 4 * i, hmine);

    // ---- dense head: logits[b][l] = db[l] + sum_i h[i] * W[i][l] ----
    const long gb = b0 + lb;
    if (active && j < LL && gb < BB) {
        float acc = db_lds[j];
        #pragma unroll
        for (int i = 0; i < HH; ++i)
            acc = fmaf(hf[i], w_lds[i * LL + j], acc);
        out[gb * LL + j] = acc;
    }
}

extern "C" void kernel_launch(void* const* d_in, const int* in_sizes, int n_in,
                              void* d_out, int out_size, void* d_ws, size_t ws_size,
                              hipStream_t stream) {
    const int* x            = (const int*)d_in[0];
    // d_in[1] = drop_rate (0.0f) -> dropout is identity; ignored.
    const float* kernelW    = (const float*)d_in[2];
    const float* rkernel    = (const float*)d_in[3];
    const float* bias       = (const float*)d_in[4];
    const float* dense_w    = (const float*)d_in[5];
    const float* dense_b    = (const float*)d_in[6];
    float* out              = (float*)d_out;

    dim3 grid((BB + NBATCH - 1) / NBATCH);   // 342 blocks
    dim3 block(NTHREADS);                    // 256 threads = 4 waves = 12 batches
    gru_kernel<<<grid, block, 0, stream>>>(x, kernelW, rkernel, bias,
                                           dense_w, dense_b, out);
}

// Round 9
// 83.402 us; speedup vs baseline: 1.7792x; 1.7792x over previous
//
#include <hip/hip_runtime.h>

// CharRNN GRU: B=4096, T=256, V=256, H=20, L=15, reset_after=True, drop_rate=0.
// f32 in / f32 out. ONE WAVE PER BLOCK, 3 batches/wave (20 lanes each).
// LDS = 160-byte h-exchange buffer ONLY (no tables, no staging, no barriers):
// per step exactly 4 DS ops (ds_write_b16 + b128 + b128 + b64, in-order pipe,
// lgkmcnt counts nothing else). xW gather = global loads (vmcnt), 2-step
// prefetched off the critical path. U packed bf16 in 30 VGPRs, dots via
// v_dot2_f32_bf16 (f32 accum), activations exp2-folded (log2e pre-scaled).

#define BB 4096
#define TT 256
#define VV 256
#define HH 20
#define G3 60    // 3*H
#define LL 15
#define L2E 1.44269504088896340736f

typedef int v4i __attribute__((ext_vector_type(4)));
typedef int v2i __attribute__((ext_vector_type(2)));

static __device__ __forceinline__ unsigned short f2bf(float f) {
    union { float f; unsigned int i; } c; c.f = f;
    unsigned int x = c.i;
    return (unsigned short)((x + 0x7FFFu + ((x >> 16) & 1u)) >> 16); // RNE
}
static __device__ __forceinline__ unsigned pack2bf(float a, float b) {
    return (unsigned)f2bf(a) | ((unsigned)f2bf(b) << 16);
}
static __device__ __forceinline__ float fast_rcp(float x) {
#if __has_builtin(__builtin_amdgcn_rcpf)
    return __builtin_amdgcn_rcpf(x);
#else
    return 1.0f / x;
#endif
}
// D = a.x*b.x + a.y*b.y + c  (bf16 pairs packed in u32, f32 accumulate)
static __device__ __forceinline__ float dot2bf(unsigned a, unsigned b, float c) {
    float d;
    asm("v_dot2_f32_bf16 %0, %1, %2, %3" : "=v"(d) : "v"(a), "v"(b), "v"(c));
    return d;
}
static __device__ __forceinline__ unsigned cvtpk(float a, float b) {
    unsigned r;
    asm("v_cvt_pk_bf16_f32 %0, %1, %2" : "=v"(r) : "v"(a), "v"(b));
    return r;
}
static __device__ __forceinline__ float exp2i(float x) {
    float r; asm("v_exp_f32 %0, %1" : "=v"(r) : "v"(x)); return r;
}
// h exchange: write my bf16 h, read my group's 20 bf16 h as 10 packed u32.
// Per-wave DS ops complete in order -> reads see this wave's write.
static __device__ __forceinline__ void h_exchange(unsigned waddr, unsigned hbf,
                                                  unsigned raddr,
                                                  v4i& p0, v4i& p1, v2i& p2) {
    asm volatile(
        "ds_write_b16 %3, %4\n\t"
        "ds_read_b128 %0, %5\n\t"
        "ds_read_b128 %1, %5 offset:16\n\t"
        "ds_read_b64 %2, %5 offset:32\n\t"
        "s_waitcnt lgkmcnt(0)"
        : "=&v"(p0), "=&v"(p1), "=&v"(p2)
        : "v"(waddr), "v"(hbf), "v"(raddr));
}

__global__ __launch_bounds__(64, 2) void gru_kernel(
    const int* __restrict__ x,            // [B][T] int32
    const float* __restrict__ kernelW,    // [V][3H] f32
    const float* __restrict__ rkernel,    // [H][3H] f32
    const float* __restrict__ bias,       // [2][3H] f32
    const float* __restrict__ dense_w,    // [H][L] f32
    const float* __restrict__ dense_b,    // [L] f32
    float* __restrict__ out)              // [B][L] f32
{
    // 3 groups * 48 B (20 bf16 + pad, 16B-aligned) + idle-lane scratch
    __shared__ __align__(16) unsigned short hbuf[80];   // 160 B total LDS

    const int lane = threadIdx.x;          // one wave per block
    const int g3a  = lane / 20;            // 0,1,2 active; 3 for lanes 60-63
    const int g3   = (lane < 60) ? g3a : 0;
    const int j    = lane - g3a * 20;      // 0..19 (idle lanes: 0..3, valid)
    const bool active = (lane < 60);
    const long b  = (long)blockIdx.x * 3 + g3;   // idle lanes alias group 0
    const long bc = (b < BB) ? b : (BB - 1);     // clamped for loads

    // zero h(0): wave-local store; address escapes via the asm, in-order pipe
    if (lane < 40) *(int*)&hbuf[lane * 2] = 0;

    const unsigned hbase = (unsigned)(size_t)&hbuf[0];
    const unsigned waddr = active ? (hbase + 48u * (unsigned)g3a + 2u * (unsigned)j)
                                  : (hbase + 144u + 2u * (unsigned)(lane - 60));
    const unsigned raddr = hbase + 48u * (unsigned)g3;

    // U columns j, H+j, 2H+j packed bf16 (pre-scaled), 30 VGPRs, from global
    unsigned Uz[10], Ur[10], Uh[10];
    #pragma unroll
    for (int q = 0; q < 10; ++q) {
        Uz[q] = pack2bf(rkernel[(2*q)*G3 + j]        * (-L2E),
                        rkernel[(2*q+1)*G3 + j]      * (-L2E));
        Ur[q] = pack2bf(rkernel[(2*q)*G3 + HH + j]   * (-L2E),
                        rkernel[(2*q+1)*G3 + HH + j] * (-L2E));
        Uh[q] = pack2bf(rkernel[(2*q)*G3 + 2*HH + j]   * (2.0f*L2E),
                        rkernel[(2*q+1)*G3 + 2*HH + j] * (2.0f*L2E));
    }
    // z/r: input + recurrent biases are additive -> one folded constant.
    // h-gate: recurrent bias brh stays inside (multiplied by r).
    const float bzc = (bias[j]        + bias[G3 + j])      * (-L2E);
    const float brc = (bias[HH + j]   + bias[G3 + HH + j]) * (-L2E);
    const float bhi =  bias[2*HH + j]                      * (2.0f*L2E);
    const float brh =  bias[G3 + 2*HH + j]                 * (2.0f*L2E);

    const int* xrow = x + bc * TT;

    // prologue: fold x-part for t=0, prefetch xv for t=1
    const int xv0 = xrow[0];
    const float* kw0 = kernelW + xv0 * G3;
    float cz = fmaf(kw0[j],        -L2E,     bzc);
    float cr = fmaf(kw0[HH + j],   -L2E,     brc);
    float ch = fmaf(kw0[2*HH + j], 2.0f*L2E, bhi);
    int xvA = xrow[1];

    float hmine = 0.0f;
    unsigned hbf = 0;

    for (int t = 0; t < TT; ++t) {
        // ---- prefetch (vmcnt, off the lgkm chain): kW(t+1) via xvA, xv(t+2)
        const float* kwn = kernelW + xvA * G3;
        const float lz = kwn[j];
        const float lr = kwn[HH + j];
        const float lh = kwn[2*HH + j];
        const int xvB = xrow[(t + 2 < TT) ? (t + 2) : (TT - 1)];

        // ---- exchange h(t): the only DS traffic in the kernel
        v4i p0, p1; v2i p2;
        h_exchange(waddr, hbf, raddr, p0, p1, p2);
        const unsigned hp[10] = { (unsigned)p0.x, (unsigned)p0.y, (unsigned)p0.z,
                                  (unsigned)p0.w, (unsigned)p1.x, (unsigned)p1.y,
                                  (unsigned)p1.z, (unsigned)p1.w, (unsigned)p2.x,
                                  (unsigned)p2.y };

        // ---- two dot2 chains per gate; accumulators seeded with x-part
        float za = cz,  ra = cr,  ha = brh;
        float zb = 0.f, rb = 0.f, hb = 0.f;
        #pragma unroll
        for (int q = 0; q < 5; ++q) {
            za = dot2bf(hp[q], Uz[q], za);
            ra = dot2bf(hp[q], Ur[q], ra);
            ha = dot2bf(hp[q], Uh[q], ha);
        }
        #pragma unroll
        for (int q = 5; q < 10; ++q) {
            zb = dot2bf(hp[q], Uz[q], zb);
            rb = dot2bf(hp[q], Ur[q], rb);
            hb = dot2bf(hp[q], Uh[q], hb);
        }

        // ---- folded activations
        const float z  = fast_rcp(1.0f + exp2i(za + zb));          // sigmoid
        const float r  = fast_rcp(1.0f + exp2i(ra + rb));          // sigmoid
        const float yh = fmaf(r, ha + hb, ch);                     // 2log2e-scaled
        const float hc = fmaf(-2.0f, fast_rcp(1.0f + exp2i(yh)), 1.0f); // tanh
        hmine = hc + z * (hmine - hc);
        hbf = cvtpk(hmine, hmine);

        // ---- commit prefetched folds for t+1
        cz = fmaf(lz, -L2E,     bzc);
        cr = fmaf(lr, -L2E,     brc);
        ch = fmaf(lh, 2.0f*L2E, bhi);
        xvA = xvB;
    }

    // final exchange to collect h(T) for the dense head
    v4i p0, p1; v2i p2;
    h_exchange(waddr, hbf, raddr, p0, p1, p2);
    const unsigned fp[10] = { (unsigned)p0.x, (unsigned)p0.y, (unsigned)p0.z,
                              (unsigned)p0.w, (unsigned)p1.x, (unsigned)p1.y,
                              (unsigned)p1.z, (unsigned)p1.w, (unsigned)p2.x,
                              (unsigned)p2.y };
    float hf[HH];
    #pragma unroll
    for (int q = 0; q < 10; ++q) {
        hf[2*q]   = __uint_as_float(fp[q] << 16);
        hf[2*q+1] = __uint_as_float(fp[q] & 0xffff0000u);
    }

    // ---- dense head: logits[b][l] = db[l] + sum_i h[i] * W[i][l]
    if (active && j < LL && b < BB) {
        float acc = dense_b[j];
        #pragma unroll
        for (int i = 0; i < HH; ++i)
            acc = fmaf(hf[i], dense_w[i * LL + j], acc);
        out[b * LL + j] = acc;
    }
}

extern "C" void kernel_launch(void* const* d_in, const int* in_sizes, int n_in,
                              void* d_out, int out_size, void* d_ws, size_t ws_size,
                              hipStream_t stream) {
    const int* x            = (const int*)d_in[0];
    // d_in[1] = drop_rate (0.0f) -> dropout is identity; ignored.
    const float* kernelW    = (const float*)d_in[2];
    const float* rkernel    = (const float*)d_in[3];
    const float* bias       = (const float*)d_in[4];
    const float* dense_w    = (const float*)d_in[5];
    const float* dense_b    = (const float*)d_in[6];
    float* out              = (float*)d_out;

    dim3 grid((BB + 2) / 3);   // 1366 one-wave blocks (5-6 per CU)
    dim3 block(64);
    gru_kernel<<<grid, block, 0, stream>>>(x, kernelW, rkernel, bias,
                                           dense_w, dense_b, out);
}